// Round 8
// baseline (232.683 us; speedup 1.0000x reference)
//
#include <hip/hip_runtime.h>

static constexpr int NND = 100000;        // nodes
static constexpr int NED = 3200000;       // edges (before self-loops)
static constexpr int NB  = (NND + 255) / 256;   // 391 buckets of 256 nodes
static constexpr int NCHUNK = 256;              // edge chunks
static constexpr int EPC = NED / NCHUNK;        // 12500 edges per chunk (=3125*4)
static constexpr int SCAN_N = NB * NCHUNK;      // 100096

typedef int int4n __attribute__((ext_vector_type(4)));   // native vec for nontemporal builtins

// ---------------- partition pass 1: per-(chunk,bucket) histogram ----------------

__global__ void k_hist(const int* __restrict__ dst, int* __restrict__ counts) {
    __shared__ int h[NB];
    for (int i = threadIdx.x; i < NB; i += 256) h[i] = 0;
    __syncthreads();
    int c = blockIdx.x;
    const int4n* d4 = reinterpret_cast<const int4n*>(dst + c * EPC);
    for (int i = threadIdx.x; i < EPC / 4; i += 256) {
        int4n v = d4[i];
        atomicAdd(&h[v.x >> 8], 1);
        atomicAdd(&h[v.y >> 8], 1);
        atomicAdd(&h[v.z >> 8], 1);
        atomicAdd(&h[v.w >> 8], 1);
    }
    __syncthreads();
    for (int b = threadIdx.x; b < NB; b += 256)
        counts[b * NCHUNK + c] = h[b];   // bucket-major for the scan
}

// ---------------- scan (exclusive), 1024 elems/block ----------------

__global__ void k_scan1(const int* __restrict__ in, int* __restrict__ excl,
                        int* __restrict__ blockSums, int n) {
    __shared__ int lds[256];
    int tid = threadIdx.x;
    int base = blockIdx.x * 1024 + tid * 4;
    int v[4]; int sum = 0;
#pragma unroll
    for (int k = 0; k < 4; ++k) { int idx = base + k; v[k] = (idx < n) ? in[idx] : 0; sum += v[k]; }
    lds[tid] = sum; __syncthreads();
    for (int off = 1; off < 256; off <<= 1) {
        int x = lds[tid];
        int y = (tid >= off) ? lds[tid - off] : 0;
        __syncthreads();
        lds[tid] = x + y;
        __syncthreads();
    }
    int run = lds[tid] - sum;
#pragma unroll
    for (int k = 0; k < 4; ++k) { int idx = base + k; if (idx < n) excl[idx] = run; run += v[k]; }
    if (tid == 0) blockSums[blockIdx.x] = lds[255];
}

__global__ void k_scan2(int* __restrict__ blockSums, int nb) {  // single block, 128 thr
    __shared__ int lds[128];
    int tid = threadIdx.x;
    int v = (tid < nb) ? blockSums[tid] : 0;
    lds[tid] = v; __syncthreads();
    for (int off = 1; off < 128; off <<= 1) {
        int x = lds[tid];
        int y = (tid >= off) ? lds[tid - off] : 0;
        __syncthreads();
        lds[tid] = x + y;
        __syncthreads();
    }
    if (tid < nb) blockSums[tid] = lds[tid] - v;
}

__global__ void k_scan3(int* __restrict__ excl, const int* __restrict__ blockSums,
                        int n, int e) {
    int i = blockIdx.x * blockDim.x + threadIdx.x;
    if (i < n) excl[i] += blockSums[i >> 10];
    if (i == n) excl[n] = e;
}

// ---------------- partition pass 2: scatter into bucket runs ----------------
// pack = src | (dst&255)<<20   (src < 2^20)

__global__ void k_part(const int* __restrict__ src, const int* __restrict__ dst,
                       const int* __restrict__ excl, int* __restrict__ tmp) {
    __shared__ int cur[NB];
    int c = blockIdx.x;
    for (int b = threadIdx.x; b < NB; b += 256) cur[b] = excl[b * NCHUNK + c];
    __syncthreads();
    const int4n* s4 = reinterpret_cast<const int4n*>(src + c * EPC);
    const int4n* d4 = reinterpret_cast<const int4n*>(dst + c * EPC);
    for (int i = threadIdx.x; i < EPC / 4; i += 256) {
        int4n sv = __builtin_nontemporal_load(&s4[i]);
        int4n dv = __builtin_nontemporal_load(&d4[i]);
        int ss[4] = {sv.x, sv.y, sv.z, sv.w};
        int dd[4] = {dv.x, dv.y, dv.z, dv.w};
#pragma unroll
        for (int k = 0; k < 4; ++k) {
            int b = dd[k] >> 8;
            int pos = atomicAdd(&cur[b], 1);
            __builtin_nontemporal_store(ss[k] | ((dd[k] & 255) << 20), &tmp[pos]);
        }
    }
}

// ------- per-bucket: deg/dinv/rowptr + CSR fill + fused layer-1 prep -------

__global__ void k_bucket(const int* __restrict__ excl, const int* __restrict__ tmp,
                         int* __restrict__ ssrc, int* __restrict__ rowptr,
                         float* __restrict__ dinv, const float* __restrict__ x,
                         float4* __restrict__ t4) {
    __shared__ int cnt[256];
    __shared__ int lds[256];
    int b = blockIdx.x, t = threadIdx.x;
    int start = excl[b * NCHUNK];
    int end   = excl[(b + 1) * NCHUNK];
    cnt[t] = 0;
    __syncthreads();
    for (int i = start + t; i < end; i += 256)
        atomicAdd(&cnt[__builtin_nontemporal_load(&tmp[i]) >> 20], 1);
    __syncthreads();
    int v = cnt[t];
    lds[t] = v; __syncthreads();
    for (int off = 1; off < 256; off <<= 1) {
        int xv = lds[t];
        int y = (t >= off) ? lds[t - off] : 0;
        __syncthreads();
        lds[t] = xv + y;
        __syncthreads();
    }
    int node = b * 256 + t;
    int rp = start + lds[t] - v;
    if (node < NND) {
        rowptr[node] = rp;
        float d = rsqrtf((float)(v + 1));  // +1 self-loop
        dinv[node] = d;
        const float* xr = x + (size_t)node * 3;   // fused layer-1 prep
        t4[node] = make_float4(xr[0] * d, xr[1] * d, xr[2] * d, 0.f);
    }
    if (b == 0 && t == 0) rowptr[NND] = NED;
    cnt[t] = rp;
    __syncthreads();
    for (int i = start + t; i < end; i += 256) {
        int p = __builtin_nontemporal_load(&tmp[i]);
        int pos = atomicAdd(&cnt[p >> 20], 1);
        ssrc[pos] = p & 0xFFFFF;
    }
}

// ------- layer1: gather 4-wide + fused 3->16 matmul -------
// t16[n,:] = relu((dinv[n]*agg)@W1+b1)*dinv[n],  agg = t4[n] + sum t4[src]

__global__ void k_g4mm1(const int* __restrict__ rowptr, const int* __restrict__ ssrc,
                        const float4* __restrict__ t4, const float* __restrict__ dinv,
                        const float* __restrict__ W1, const float* __restrict__ b1,
                        float* __restrict__ t16, int n) {
    __shared__ float sW[48];
    __shared__ float sb[16];
    if (threadIdx.x < 48) sW[threadIdx.x] = W1[threadIdx.x];
    if (threadIdx.x < 16) sb[threadIdx.x] = b1[threadIdx.x];
    __syncthreads();
    int node = blockIdx.x * blockDim.x + threadIdx.x;
    if (node >= n) return;

    float4 a = t4[node];
    float a0 = a.x, a1 = a.y, a2 = a.z;
    int beg = rowptr[node], end = rowptr[node + 1];
    constexpr int U = 8;
    int j = beg;
    for (; j + U <= end; j += U) {
        int s[U];
#pragma unroll
        for (int k = 0; k < U; ++k) s[k] = ssrc[j + k];
        float4 v[U];
#pragma unroll
        for (int k = 0; k < U; ++k) v[k] = t4[s[k]];
#pragma unroll
        for (int k = 0; k < U; ++k) { a0 += v[k].x; a1 += v[k].y; a2 += v[k].z; }
    }
    for (; j < end; ++j) {
        float4 v = t4[ssrc[j]];
        a0 += v.x; a1 += v.y; a2 += v.z;
    }
    float d = dinv[node];
    float p0 = a0 * d, p1 = a1 * d, p2 = a2 * d;
    float* orow = t16 + (size_t)node * 16;
#pragma unroll
    for (int q = 0; q < 4; ++q) {
        float4 o;
        float* op = reinterpret_cast<float*>(&o);
#pragma unroll
        for (int r = 0; r < 4; ++r) {
            int jj = q * 4 + r;
            float h = fmaf(p0, sW[jj], fmaf(p1, sW[16 + jj], fmaf(p2, sW[32 + jj], sb[jj])));
            op[r] = fmaxf(h, 0.f) * d;
        }
        *reinterpret_cast<float4*>(orow + q * 4) = o;
    }
}

// ------- layer2: 16-wide gather + fused W2/relu/W3 epilogue -------
// 4 lanes per node; after gather, quad all-gathers u[16] via shfl_xor and
// computes t3 = (relu(u@W2+b2)@W3)*dinv directly.

__global__ void k_g16mm(const int* __restrict__ rowptr, const int* __restrict__ ssrc,
                        const float* __restrict__ t16, const float* __restrict__ dinv,
                        const float* __restrict__ W2, const float* __restrict__ b2,
                        const float* __restrict__ W3, float2* __restrict__ t3, int n) {
    __shared__ float sW2[512];
    __shared__ float sb2[32];
    __shared__ float sW3[64];
    for (int i = threadIdx.x; i < 512; i += 256) sW2[i] = W2[i];
    if (threadIdx.x < 32) sb2[threadIdx.x] = b2[threadIdx.x];
    if (threadIdx.x < 64) sW3[threadIdx.x] = W3[threadIdx.x];
    __syncthreads();

    constexpr int U = 8;
    int i = blockIdx.x * blockDim.x + threadIdx.x;
    int node = i >> 2;
    int fv = i & 3;          // quad lane: owns feats fv*4..fv*4+3
    if (node >= n) return;   // whole quads exit together (4-aligned)
    int f0 = fv * 4;

    float4 acc = *reinterpret_cast<const float4*>(t16 + (size_t)node * 16 + f0);
    int beg = rowptr[node], end = rowptr[node + 1];
    int j = beg;
    for (; j + U <= end; j += U) {
        int s[U];
#pragma unroll
        for (int k = 0; k < U; ++k) s[k] = ssrc[j + k];
        float4 v[U];
#pragma unroll
        for (int k = 0; k < U; ++k)
            v[k] = *reinterpret_cast<const float4*>(t16 + (size_t)s[k] * 16 + f0);
#pragma unroll
        for (int k = 0; k < U; ++k) {
            acc.x += v[k].x; acc.y += v[k].y; acc.z += v[k].z; acc.w += v[k].w;
        }
    }
    for (; j < end; ++j) {
        float4 v = *reinterpret_cast<const float4*>(t16 + (size_t)ssrc[j] * 16 + f0);
        acc.x += v.x; acc.y += v.y; acc.z += v.z; acc.w += v.w;
    }
    float d = dinv[node];
    float q[4] = {acc.x * d, acc.y * d, acc.z * d, acc.w * d};  // u[f0..f0+3]

    // quad all-gather: p1 = quad(fv^1), p2 = quad(fv^2), p3 = quad(fv^3)
    float p1[4], p2[4], p3[4];
#pragma unroll
    for (int c = 0; c < 4; ++c) p1[c] = __shfl_xor(q[c], 1);
#pragma unroll
    for (int c = 0; c < 4; ++c) { p2[c] = __shfl_xor(q[c], 2); p3[c] = __shfl_xor(p1[c], 2); }

    float uu[16];
#pragma unroll
    for (int c = 0; c < 4; ++c) {
        uu[0 + c]  = fv == 0 ? q[c] : fv == 1 ? p1[c] : fv == 2 ? p2[c] : p3[c];
        uu[4 + c]  = fv == 1 ? q[c] : fv == 0 ? p1[c] : fv == 3 ? p2[c] : p3[c];
        uu[8 + c]  = fv == 2 ? q[c] : fv == 3 ? p1[c] : fv == 0 ? p2[c] : p3[c];
        uu[12 + c] = fv == 3 ? q[c] : fv == 2 ? p1[c] : fv == 1 ? p2[c] : p3[c];
    }

    // lane fv computes W2 columns fv*8..fv*8+7
    float t30 = 0.f, t31 = 0.f;
    int jbase = fv * 8;
#pragma unroll
    for (int r = 0; r < 8; ++r) {
        int jj = jbase + r;
        float h = sb2[jj];
#pragma unroll
        for (int k = 0; k < 16; ++k) h = fmaf(uu[k], sW2[k * 32 + jj], h);
        h = fmaxf(h, 0.f);
        t30 = fmaf(h, sW3[jj * 2 + 0], t30);
        t31 = fmaf(h, sW3[jj * 2 + 1], t31);
    }
    t30 += __shfl_xor(t30, 1); t30 += __shfl_xor(t30, 2);
    t31 += __shfl_xor(t31, 1); t31 += __shfl_xor(t31, 2);
    if (fv == 0) t3[node] = make_float2(t30 * d, t31 * d);
}

// ---------------- layer3: gather 2-wide + bias ----------------

__global__ void k_g2(const int* __restrict__ rowptr, const int* __restrict__ ssrc,
                     const float2* __restrict__ t3, const float* __restrict__ dinv,
                     const float* __restrict__ b3, float2* __restrict__ out, int n) {
    constexpr int U = 8;
    int node = blockIdx.x * blockDim.x + threadIdx.x;
    if (node >= n) return;
    float2 t = t3[node];
    float a0 = t.x, a1 = t.y;
    int beg = rowptr[node], end = rowptr[node + 1];
    int j = beg;
    for (; j + U <= end; j += U) {
        int s[U];
#pragma unroll
        for (int k = 0; k < U; ++k) s[k] = ssrc[j + k];
        float2 v[U];
#pragma unroll
        for (int k = 0; k < U; ++k) v[k] = t3[s[k]];
#pragma unroll
        for (int k = 0; k < U; ++k) { a0 += v[k].x; a1 += v[k].y; }
    }
    for (; j < end; ++j) {
        float2 v = t3[ssrc[j]];
        a0 += v.x; a1 += v.y;
    }
    float d = dinv[node];
    out[node] = make_float2(fmaf(d, a0, b3[0]), fmaf(d, a1, b3[1]));
}

// ---------------- launch ----------------

static inline size_t align256(size_t x) { return (x + 255) & ~(size_t)255; }

extern "C" void kernel_launch(void* const* d_in, const int* in_sizes, int n_in,
                              void* d_out, int out_size, void* d_ws, size_t ws_size,
                              hipStream_t stream) {
    const float* x  = (const float*)d_in[0];
    const int*   ei = (const int*)d_in[1];
    const float* W1 = (const float*)d_in[2];
    const float* b1 = (const float*)d_in[3];
    const float* W2 = (const float*)d_in[4];
    const float* b2 = (const float*)d_in[5];
    const float* W3 = (const float*)d_in[6];
    const float* b3 = (const float*)d_in[7];
    float2* out = (float2*)d_out;

    const int* src = ei;
    const int* dst = ei + NED;

    char* p = (char*)d_ws;
    float* dinv   = (float*)p; p += align256(sizeof(float) * (size_t)NND);
    int*   rowptr = (int*)p;   p += align256(sizeof(int) * (size_t)(NND + 1));
    int*   excl   = (int*)p;   p += align256(sizeof(int) * (size_t)(SCAN_N + 1));
    int*   bsums  = (int*)p;   p += align256(sizeof(int) * 128);
    int*   ssrc   = (int*)p;   p += align256(sizeof(int) * (size_t)NED);
    float4* t4    = (float4*)p; p += align256(sizeof(float4) * (size_t)NND);
    float2* t3    = (float2*)p; p += align256(sizeof(float2) * (size_t)NND);
    // region shared by tmp (dead after k_bucket) and t16 (written after)
    char*  q      = p;         p += align256(sizeof(int) * (size_t)NED);
    int*   tmp    = (int*)q;
    float* t16    = (float*)q;                                   // [NND][16]

    const int B = 256;
    const int gridN = (NND + B - 1) / B;
    const int grid4N = (NND * 4 + B - 1) / B;
    const int nScanBlocks = (SCAN_N + 1023) / 1024;  // 98

    // ---- CSR build (+ fused layer-1 prep in k_bucket) ----
    k_hist<<<NCHUNK, B, 0, stream>>>(dst, excl);
    k_scan1<<<nScanBlocks, 256, 0, stream>>>(excl, excl, bsums, SCAN_N);
    k_scan2<<<1, 128, 0, stream>>>(bsums, nScanBlocks);
    k_scan3<<<(SCAN_N + 1 + B - 1) / B, B, 0, stream>>>(excl, bsums, SCAN_N, NED);
    k_part<<<NCHUNK, B, 0, stream>>>(src, dst, excl, tmp);
    k_bucket<<<NB, B, 0, stream>>>(excl, tmp, ssrc, rowptr, dinv, x, t4);

    // ---- layer 1: aggregate 4-wide, fused 3->16 ----
    k_g4mm1<<<gridN, B, 0, stream>>>(rowptr, ssrc, t4, dinv, W1, b1, t16, NND);

    // ---- layer 2: 16-wide gather + fused W2/relu/W3 -> t3 ----
    k_g16mm<<<grid4N, B, 0, stream>>>(rowptr, ssrc, t16, dinv, W2, b2, W3, t3, NND);

    // ---- layer 3: gather 2-wide ----
    k_g2<<<gridN, B, 0, stream>>>(rowptr, ssrc, t3, dinv, b3, out, NND);
}

// Round 9
// 166.287 us; speedup vs baseline: 1.3993x; 1.3993x over previous
//
#include <hip/hip_runtime.h>

static constexpr int NND = 100000;        // nodes
static constexpr int NED = 3200000;       // edges (before self-loops)
static constexpr int NB  = (NND + 255) / 256;   // 391 buckets of 256 nodes
static constexpr int NCHUNK = 256;              // edge chunks
static constexpr int EPC = NED / NCHUNK;        // 12500 edges per chunk (=3125*4)
static constexpr int SCAN_N = NB * NCHUNK;      // 100096

typedef int int4n __attribute__((ext_vector_type(4)));   // native vec for nontemporal builtins

// ---------------- partition pass 1: per-(chunk,bucket) histogram ----------------

__global__ void k_hist(const int* __restrict__ dst, int* __restrict__ counts) {
    __shared__ int h[NB];
    for (int i = threadIdx.x; i < NB; i += 256) h[i] = 0;
    __syncthreads();
    int c = blockIdx.x;
    const int4n* d4 = reinterpret_cast<const int4n*>(dst + c * EPC);
    for (int i = threadIdx.x; i < EPC / 4; i += 256) {
        int4n v = d4[i];
        atomicAdd(&h[v.x >> 8], 1);
        atomicAdd(&h[v.y >> 8], 1);
        atomicAdd(&h[v.z >> 8], 1);
        atomicAdd(&h[v.w >> 8], 1);
    }
    __syncthreads();
    for (int b = threadIdx.x; b < NB; b += 256)
        counts[b * NCHUNK + c] = h[b];   // bucket-major for the scan
}

// ---------------- scan (exclusive), 1024 elems/block ----------------

__global__ void k_scan1(const int* __restrict__ in, int* __restrict__ excl,
                        int* __restrict__ blockSums, int n) {
    __shared__ int lds[256];
    int tid = threadIdx.x;
    int base = blockIdx.x * 1024 + tid * 4;
    int v[4]; int sum = 0;
#pragma unroll
    for (int k = 0; k < 4; ++k) { int idx = base + k; v[k] = (idx < n) ? in[idx] : 0; sum += v[k]; }
    lds[tid] = sum; __syncthreads();
    for (int off = 1; off < 256; off <<= 1) {
        int x = lds[tid];
        int y = (tid >= off) ? lds[tid - off] : 0;
        __syncthreads();
        lds[tid] = x + y;
        __syncthreads();
    }
    int run = lds[tid] - sum;
#pragma unroll
    for (int k = 0; k < 4; ++k) { int idx = base + k; if (idx < n) excl[idx] = run; run += v[k]; }
    if (tid == 0) blockSums[blockIdx.x] = lds[255];
}

__global__ void k_scan2(int* __restrict__ blockSums, int nb) {  // single block, 128 thr
    __shared__ int lds[128];
    int tid = threadIdx.x;
    int v = (tid < nb) ? blockSums[tid] : 0;
    lds[tid] = v; __syncthreads();
    for (int off = 1; off < 128; off <<= 1) {
        int x = lds[tid];
        int y = (tid >= off) ? lds[tid - off] : 0;
        __syncthreads();
        lds[tid] = x + y;
        __syncthreads();
    }
    if (tid < nb) blockSums[tid] = lds[tid] - v;
}

__global__ void k_scan3(int* __restrict__ excl, const int* __restrict__ blockSums,
                        int n, int e) {
    int i = blockIdx.x * blockDim.x + threadIdx.x;
    if (i < n) excl[i] += blockSums[i >> 10];
    if (i == n) excl[n] = e;
}

// ---------------- partition pass 2: scatter into bucket runs ----------------
// pack = src | (dst&255)<<20   (src < 2^20)

__global__ void k_part(const int* __restrict__ src, const int* __restrict__ dst,
                       const int* __restrict__ excl, int* __restrict__ tmp) {
    __shared__ int cur[NB];
    int c = blockIdx.x;
    for (int b = threadIdx.x; b < NB; b += 256) cur[b] = excl[b * NCHUNK + c];
    __syncthreads();
    const int4n* s4 = reinterpret_cast<const int4n*>(src + c * EPC);
    const int4n* d4 = reinterpret_cast<const int4n*>(dst + c * EPC);
    for (int i = threadIdx.x; i < EPC / 4; i += 256) {
        int4n sv = __builtin_nontemporal_load(&s4[i]);   // src/dst: genuinely last-read here
        int4n dv = __builtin_nontemporal_load(&d4[i]);
        int ss[4] = {sv.x, sv.y, sv.z, sv.w};
        int dd[4] = {dv.x, dv.y, dv.z, dv.w};
#pragma unroll
        for (int k = 0; k < 4; ++k) {
            int b = dd[k] >> 8;
            int pos = atomicAdd(&cur[b], 1);
            tmp[pos] = ss[k] | ((dd[k] & 255) << 20);    // PLAIN store: L2 write-combines runs
        }
    }
}

// ------- per-bucket: deg/dinv/rowptr + CSR fill + fused layer-1 prep -------

__global__ void k_bucket(const int* __restrict__ excl, const int* __restrict__ tmp,
                         int* __restrict__ ssrc, int* __restrict__ rowptr,
                         float* __restrict__ dinv, const float* __restrict__ x,
                         float4* __restrict__ t4) {
    __shared__ int cnt[256];
    __shared__ int lds[256];
    int b = blockIdx.x, t = threadIdx.x;
    int start = excl[b * NCHUNK];
    int end   = excl[(b + 1) * NCHUNK];
    cnt[t] = 0;
    __syncthreads();
    for (int i = start + t; i < end; i += 256)
        atomicAdd(&cnt[tmp[i] >> 20], 1);   // plain load: tmp is read twice (here + fill)
    __syncthreads();
    int v = cnt[t];
    lds[t] = v; __syncthreads();
    for (int off = 1; off < 256; off <<= 1) {
        int xv = lds[t];
        int y = (t >= off) ? lds[t - off] : 0;
        __syncthreads();
        lds[t] = xv + y;
        __syncthreads();
    }
    int node = b * 256 + t;
    int rp = start + lds[t] - v;
    if (node < NND) {
        rowptr[node] = rp;
        float d = rsqrtf((float)(v + 1));  // +1 self-loop
        dinv[node] = d;
        const float* xr = x + (size_t)node * 3;   // fused layer-1 prep
        t4[node] = make_float4(xr[0] * d, xr[1] * d, xr[2] * d, 0.f);
    }
    if (b == 0 && t == 0) rowptr[NND] = NED;
    cnt[t] = rp;
    __syncthreads();
    for (int i = start + t; i < end; i += 256) {
        int p = tmp[i];
        int pos = atomicAdd(&cnt[p >> 20], 1);
        ssrc[pos] = p & 0xFFFFF;
    }
}

// ------- layer1: gather 4-wide + fused 3->16 matmul -------
// t16[n,:] = relu((dinv[n]*agg)@W1+b1)*dinv[n],  agg = t4[n] + sum t4[src]

__global__ void k_g4mm1(const int* __restrict__ rowptr, const int* __restrict__ ssrc,
                        const float4* __restrict__ t4, const float* __restrict__ dinv,
                        const float* __restrict__ W1, const float* __restrict__ b1,
                        float* __restrict__ t16, int n) {
    __shared__ float sW[48];
    __shared__ float sb[16];
    if (threadIdx.x < 48) sW[threadIdx.x] = W1[threadIdx.x];
    if (threadIdx.x < 16) sb[threadIdx.x] = b1[threadIdx.x];
    __syncthreads();
    int node = blockIdx.x * blockDim.x + threadIdx.x;
    if (node >= n) return;

    float4 a = t4[node];
    float a0 = a.x, a1 = a.y, a2 = a.z;
    int beg = rowptr[node], end = rowptr[node + 1];
    constexpr int U = 8;
    int j = beg;
    for (; j + U <= end; j += U) {
        int s[U];
#pragma unroll
        for (int k = 0; k < U; ++k) s[k] = ssrc[j + k];
        float4 v[U];
#pragma unroll
        for (int k = 0; k < U; ++k) v[k] = t4[s[k]];
#pragma unroll
        for (int k = 0; k < U; ++k) { a0 += v[k].x; a1 += v[k].y; a2 += v[k].z; }
    }
    for (; j < end; ++j) {
        float4 v = t4[ssrc[j]];
        a0 += v.x; a1 += v.y; a2 += v.z;
    }
    float d = dinv[node];
    float p0 = a0 * d, p1 = a1 * d, p2 = a2 * d;
    float* orow = t16 + (size_t)node * 16;
#pragma unroll
    for (int q = 0; q < 4; ++q) {
        float4 o;
        float* op = reinterpret_cast<float*>(&o);
#pragma unroll
        for (int r = 0; r < 4; ++r) {
            int jj = q * 4 + r;
            float h = fmaf(p0, sW[jj], fmaf(p1, sW[16 + jj], fmaf(p2, sW[32 + jj], sb[jj])));
            op[r] = fmaxf(h, 0.f) * d;
        }
        *reinterpret_cast<float4*>(orow + q * 4) = o;
    }
}

// ------- layer2: 16-wide gather + fused W2/relu/W3 epilogue -------
// 4 lanes per node; after gather, quad all-gathers u[16] via shfl_xor and
// computes t3 = (relu(u@W2+b2)@W3)*dinv directly.

__global__ void k_g16mm(const int* __restrict__ rowptr, const int* __restrict__ ssrc,
                        const float* __restrict__ t16, const float* __restrict__ dinv,
                        const float* __restrict__ W2, const float* __restrict__ b2,
                        const float* __restrict__ W3, float2* __restrict__ t3, int n) {
    __shared__ float sW2[512];
    __shared__ float sb2[32];
    __shared__ float sW3[64];
    for (int i = threadIdx.x; i < 512; i += 256) sW2[i] = W2[i];
    if (threadIdx.x < 32) sb2[threadIdx.x] = b2[threadIdx.x];
    if (threadIdx.x < 64) sW3[threadIdx.x] = W3[threadIdx.x];
    __syncthreads();

    constexpr int U = 8;
    int i = blockIdx.x * blockDim.x + threadIdx.x;
    int node = i >> 2;
    int fv = i & 3;          // quad lane: owns feats fv*4..fv*4+3
    if (node >= n) return;   // whole quads exit together (4-aligned)
    int f0 = fv * 4;

    float4 acc = *reinterpret_cast<const float4*>(t16 + (size_t)node * 16 + f0);
    int beg = rowptr[node], end = rowptr[node + 1];
    int j = beg;
    for (; j + U <= end; j += U) {
        int s[U];
#pragma unroll
        for (int k = 0; k < U; ++k) s[k] = ssrc[j + k];
        float4 v[U];
#pragma unroll
        for (int k = 0; k < U; ++k)
            v[k] = *reinterpret_cast<const float4*>(t16 + (size_t)s[k] * 16 + f0);
#pragma unroll
        for (int k = 0; k < U; ++k) {
            acc.x += v[k].x; acc.y += v[k].y; acc.z += v[k].z; acc.w += v[k].w;
        }
    }
    for (; j < end; ++j) {
        float4 v = *reinterpret_cast<const float4*>(t16 + (size_t)ssrc[j] * 16 + f0);
        acc.x += v.x; acc.y += v.y; acc.z += v.z; acc.w += v.w;
    }
    float d = dinv[node];
    float q[4] = {acc.x * d, acc.y * d, acc.z * d, acc.w * d};  // u[f0..f0+3]

    // quad all-gather: p1 = quad(fv^1), p2 = quad(fv^2), p3 = quad(fv^3)
    float p1[4], p2[4], p3[4];
#pragma unroll
    for (int c = 0; c < 4; ++c) p1[c] = __shfl_xor(q[c], 1);
#pragma unroll
    for (int c = 0; c < 4; ++c) { p2[c] = __shfl_xor(q[c], 2); p3[c] = __shfl_xor(p1[c], 2); }

    float uu[16];
#pragma unroll
    for (int c = 0; c < 4; ++c) {
        uu[0 + c]  = fv == 0 ? q[c] : fv == 1 ? p1[c] : fv == 2 ? p2[c] : p3[c];
        uu[4 + c]  = fv == 1 ? q[c] : fv == 0 ? p1[c] : fv == 3 ? p2[c] : p3[c];
        uu[8 + c]  = fv == 2 ? q[c] : fv == 3 ? p1[c] : fv == 0 ? p2[c] : p3[c];
        uu[12 + c] = fv == 3 ? q[c] : fv == 2 ? p1[c] : fv == 1 ? p2[c] : p3[c];
    }

    // lane fv computes W2 columns fv*8..fv*8+7
    float t30 = 0.f, t31 = 0.f;
    int jbase = fv * 8;
#pragma unroll
    for (int r = 0; r < 8; ++r) {
        int jj = jbase + r;
        float h = sb2[jj];
#pragma unroll
        for (int k = 0; k < 16; ++k) h = fmaf(uu[k], sW2[k * 32 + jj], h);
        h = fmaxf(h, 0.f);
        t30 = fmaf(h, sW3[jj * 2 + 0], t30);
        t31 = fmaf(h, sW3[jj * 2 + 1], t31);
    }
    t30 += __shfl_xor(t30, 1); t30 += __shfl_xor(t30, 2);
    t31 += __shfl_xor(t31, 1); t31 += __shfl_xor(t31, 2);
    if (fv == 0) t3[node] = make_float2(t30 * d, t31 * d);
}

// ---------------- layer3: gather 2-wide + bias ----------------

__global__ void k_g2(const int* __restrict__ rowptr, const int* __restrict__ ssrc,
                     const float2* __restrict__ t3, const float* __restrict__ dinv,
                     const float* __restrict__ b3, float2* __restrict__ out, int n) {
    constexpr int U = 8;
    int node = blockIdx.x * blockDim.x + threadIdx.x;
    if (node >= n) return;
    float2 t = t3[node];
    float a0 = t.x, a1 = t.y;
    int beg = rowptr[node], end = rowptr[node + 1];
    int j = beg;
    for (; j + U <= end; j += U) {
        int s[U];
#pragma unroll
        for (int k = 0; k < U; ++k) s[k] = ssrc[j + k];
        float2 v[U];
#pragma unroll
        for (int k = 0; k < U; ++k) v[k] = t3[s[k]];
#pragma unroll
        for (int k = 0; k < U; ++k) { a0 += v[k].x; a1 += v[k].y; }
    }
    for (; j < end; ++j) {
        float2 v = t3[ssrc[j]];
        a0 += v.x; a1 += v.y;
    }
    float d = dinv[node];
    out[node] = make_float2(fmaf(d, a0, b3[0]), fmaf(d, a1, b3[1]));
}

// ---------------- launch ----------------

static inline size_t align256(size_t x) { return (x + 255) & ~(size_t)255; }

extern "C" void kernel_launch(void* const* d_in, const int* in_sizes, int n_in,
                              void* d_out, int out_size, void* d_ws, size_t ws_size,
                              hipStream_t stream) {
    const float* x  = (const float*)d_in[0];
    const int*   ei = (const int*)d_in[1];
    const float* W1 = (const float*)d_in[2];
    const float* b1 = (const float*)d_in[3];
    const float* W2 = (const float*)d_in[4];
    const float* b2 = (const float*)d_in[5];
    const float* W3 = (const float*)d_in[6];
    const float* b3 = (const float*)d_in[7];
    float2* out = (float2*)d_out;

    const int* src = ei;
    const int* dst = ei + NED;

    char* p = (char*)d_ws;
    float* dinv   = (float*)p; p += align256(sizeof(float) * (size_t)NND);
    int*   rowptr = (int*)p;   p += align256(sizeof(int) * (size_t)(NND + 1));
    int*   excl   = (int*)p;   p += align256(sizeof(int) * (size_t)(SCAN_N + 1));
    int*   bsums  = (int*)p;   p += align256(sizeof(int) * 128);
    int*   ssrc   = (int*)p;   p += align256(sizeof(int) * (size_t)NED);
    float4* t4    = (float4*)p; p += align256(sizeof(float4) * (size_t)NND);
    float2* t3    = (float2*)p; p += align256(sizeof(float2) * (size_t)NND);
    // region shared by tmp (dead after k_bucket) and t16 (written after)
    char*  q      = p;         p += align256(sizeof(int) * (size_t)NED);
    int*   tmp    = (int*)q;
    float* t16    = (float*)q;                                   // [NND][16]

    const int B = 256;
    const int gridN = (NND + B - 1) / B;
    const int grid4N = (NND * 4 + B - 1) / B;
    const int nScanBlocks = (SCAN_N + 1023) / 1024;  // 98

    // ---- CSR build (+ fused layer-1 prep in k_bucket) ----
    k_hist<<<NCHUNK, B, 0, stream>>>(dst, excl);
    k_scan1<<<nScanBlocks, 256, 0, stream>>>(excl, excl, bsums, SCAN_N);
    k_scan2<<<1, 128, 0, stream>>>(bsums, nScanBlocks);
    k_scan3<<<(SCAN_N + 1 + B - 1) / B, B, 0, stream>>>(excl, bsums, SCAN_N, NED);
    k_part<<<NCHUNK, B, 0, stream>>>(src, dst, excl, tmp);
    k_bucket<<<NB, B, 0, stream>>>(excl, tmp, ssrc, rowptr, dinv, x, t4);

    // ---- layer 1: aggregate 4-wide, fused 3->16 ----
    k_g4mm1<<<gridN, B, 0, stream>>>(rowptr, ssrc, t4, dinv, W1, b1, t16, NND);

    // ---- layer 2: 16-wide gather + fused W2/relu/W3 -> t3 ----
    k_g16mm<<<grid4N, B, 0, stream>>>(rowptr, ssrc, t16, dinv, W2, b2, W3, t3, NND);

    // ---- layer 3: gather 2-wide ----
    k_g2<<<gridN, B, 0, stream>>>(rowptr, ssrc, t3, dinv, b3, out, NND);
}

// Round 10
// 153.303 us; speedup vs baseline: 1.5178x; 1.0847x over previous
//
#include <hip/hip_runtime.h>

static constexpr int NND = 100000;        // nodes
static constexpr int NED = 3200000;       // edges (before self-loops)
static constexpr int NB  = (NND + 255) / 256;   // 391 buckets of 256 nodes
static constexpr int NCHUNK = 256;              // edge chunks
static constexpr int EPC = NED / NCHUNK;        // 12500 edges per chunk (=3125*4)
static constexpr int SCAN_N = NB * NCHUNK;      // 100096

typedef int int4n __attribute__((ext_vector_type(4)));        // native vec for nontemporal builtins
typedef _Float16 half4n __attribute__((ext_vector_type(4)));  // 8 B fp16 quad
typedef _Float16 half8n __attribute__((ext_vector_type(8)));  // 16 B fp16 oct

// ---------------- partition pass 1: per-(chunk,bucket) histogram ----------------

__global__ void k_hist(const int* __restrict__ dst, int* __restrict__ counts) {
    __shared__ int h[NB];
    for (int i = threadIdx.x; i < NB; i += 256) h[i] = 0;
    __syncthreads();
    int c = blockIdx.x;
    const int4n* d4 = reinterpret_cast<const int4n*>(dst + c * EPC);
    for (int i = threadIdx.x; i < EPC / 4; i += 256) {
        int4n v = d4[i];
        atomicAdd(&h[v.x >> 8], 1);
        atomicAdd(&h[v.y >> 8], 1);
        atomicAdd(&h[v.z >> 8], 1);
        atomicAdd(&h[v.w >> 8], 1);
    }
    __syncthreads();
    for (int b = threadIdx.x; b < NB; b += 256)
        counts[b * NCHUNK + c] = h[b];   // bucket-major for the scan
}

// ---------------- scan (exclusive), 1024 elems/block ----------------

__global__ void k_scan1(const int* __restrict__ in, int* __restrict__ excl,
                        int* __restrict__ blockSums, int n) {
    __shared__ int lds[256];
    int tid = threadIdx.x;
    int base = blockIdx.x * 1024 + tid * 4;
    int v[4]; int sum = 0;
#pragma unroll
    for (int k = 0; k < 4; ++k) { int idx = base + k; v[k] = (idx < n) ? in[idx] : 0; sum += v[k]; }
    lds[tid] = sum; __syncthreads();
    for (int off = 1; off < 256; off <<= 1) {
        int x = lds[tid];
        int y = (tid >= off) ? lds[tid - off] : 0;
        __syncthreads();
        lds[tid] = x + y;
        __syncthreads();
    }
    int run = lds[tid] - sum;
#pragma unroll
    for (int k = 0; k < 4; ++k) { int idx = base + k; if (idx < n) excl[idx] = run; run += v[k]; }
    if (tid == 0) blockSums[blockIdx.x] = lds[255];
}

__global__ void k_scan2(int* __restrict__ blockSums, int nb) {  // single block, 128 thr
    __shared__ int lds[128];
    int tid = threadIdx.x;
    int v = (tid < nb) ? blockSums[tid] : 0;
    lds[tid] = v; __syncthreads();
    for (int off = 1; off < 128; off <<= 1) {
        int x = lds[tid];
        int y = (tid >= off) ? lds[tid - off] : 0;
        __syncthreads();
        lds[tid] = x + y;
        __syncthreads();
    }
    if (tid < nb) blockSums[tid] = lds[tid] - v;
}

__global__ void k_scan3(int* __restrict__ excl, const int* __restrict__ blockSums,
                        int n, int e) {
    int i = blockIdx.x * blockDim.x + threadIdx.x;
    if (i < n) excl[i] += blockSums[i >> 10];
    if (i == n) excl[n] = e;
}

// ---------------- partition pass 2: scatter into bucket runs ----------------
// pack = src | (dst&255)<<20   (src < 2^20)

__global__ void k_part(const int* __restrict__ src, const int* __restrict__ dst,
                       const int* __restrict__ excl, int* __restrict__ tmp) {
    __shared__ int cur[NB];
    int c = blockIdx.x;
    for (int b = threadIdx.x; b < NB; b += 256) cur[b] = excl[b * NCHUNK + c];
    __syncthreads();
    const int4n* s4 = reinterpret_cast<const int4n*>(src + c * EPC);
    const int4n* d4 = reinterpret_cast<const int4n*>(dst + c * EPC);
    for (int i = threadIdx.x; i < EPC / 4; i += 256) {
        int4n sv = __builtin_nontemporal_load(&s4[i]);   // src/dst: genuinely last-read here
        int4n dv = __builtin_nontemporal_load(&d4[i]);
        int ss[4] = {sv.x, sv.y, sv.z, sv.w};
        int dd[4] = {dv.x, dv.y, dv.z, dv.w};
#pragma unroll
        for (int k = 0; k < 4; ++k) {
            int b = dd[k] >> 8;
            int pos = atomicAdd(&cur[b], 1);
            tmp[pos] = ss[k] | ((dd[k] & 255) << 20);    // PLAIN store: L2 write-combines runs
        }
    }
}

// ------- per-bucket: deg/dinv/rowptr + CSR fill + fused layer-1 prep -------

__global__ void k_bucket(const int* __restrict__ excl, const int* __restrict__ tmp,
                         int* __restrict__ ssrc, int* __restrict__ rowptr,
                         float* __restrict__ dinv, const float* __restrict__ x,
                         float4* __restrict__ t4) {
    __shared__ int cnt[256];
    __shared__ int lds[256];
    int b = blockIdx.x, t = threadIdx.x;
    int start = excl[b * NCHUNK];
    int end   = excl[(b + 1) * NCHUNK];
    cnt[t] = 0;
    __syncthreads();
    for (int i = start + t; i < end; i += 256)
        atomicAdd(&cnt[tmp[i] >> 20], 1);
    __syncthreads();
    int v = cnt[t];
    lds[t] = v; __syncthreads();
    for (int off = 1; off < 256; off <<= 1) {
        int xv = lds[t];
        int y = (t >= off) ? lds[t - off] : 0;
        __syncthreads();
        lds[t] = xv + y;
        __syncthreads();
    }
    int node = b * 256 + t;
    int rp = start + lds[t] - v;
    if (node < NND) {
        rowptr[node] = rp;
        float d = rsqrtf((float)(v + 1));  // +1 self-loop
        dinv[node] = d;
        const float* xr = x + (size_t)node * 3;   // fused layer-1 prep
        t4[node] = make_float4(xr[0] * d, xr[1] * d, xr[2] * d, 0.f);
    }
    if (b == 0 && t == 0) rowptr[NND] = NED;
    cnt[t] = rp;
    __syncthreads();
    for (int i = start + t; i < end; i += 256) {
        int p = tmp[i];
        int pos = atomicAdd(&cnt[p >> 20], 1);
        ssrc[pos] = p & 0xFFFFF;
    }
}

// ------- layer1: gather 4-wide + fused 3->16 matmul, fp16 table out -------
// t16[n,:] = (fp16) relu((dinv[n]*agg)@W1+b1)*dinv[n],  agg = t4[n] + sum t4[src]

__global__ void k_g4mm1(const int* __restrict__ rowptr, const int* __restrict__ ssrc,
                        const float4* __restrict__ t4, const float* __restrict__ dinv,
                        const float* __restrict__ W1, const float* __restrict__ b1,
                        _Float16* __restrict__ t16, int n) {
    __shared__ float sW[48];
    __shared__ float sb[16];
    if (threadIdx.x < 48) sW[threadIdx.x] = W1[threadIdx.x];
    if (threadIdx.x < 16) sb[threadIdx.x] = b1[threadIdx.x];
    __syncthreads();
    int node = blockIdx.x * blockDim.x + threadIdx.x;
    if (node >= n) return;

    float4 a = t4[node];
    float a0 = a.x, a1 = a.y, a2 = a.z;
    int beg = rowptr[node], end = rowptr[node + 1];
    constexpr int U = 8;
    int j = beg;
    for (; j + U <= end; j += U) {
        int s[U];
#pragma unroll
        for (int k = 0; k < U; ++k) s[k] = ssrc[j + k];
        float4 v[U];
#pragma unroll
        for (int k = 0; k < U; ++k) v[k] = t4[s[k]];
#pragma unroll
        for (int k = 0; k < U; ++k) { a0 += v[k].x; a1 += v[k].y; a2 += v[k].z; }
    }
    for (; j < end; ++j) {
        float4 v = t4[ssrc[j]];
        a0 += v.x; a1 += v.y; a2 += v.z;
    }
    float d = dinv[node];
    float p0 = a0 * d, p1 = a1 * d, p2 = a2 * d;
    _Float16* orow = t16 + (size_t)node * 16;
#pragma unroll
    for (int q = 0; q < 2; ++q) {
        half8n o;
#pragma unroll
        for (int r = 0; r < 8; ++r) {
            int jj = q * 8 + r;
            float h = fmaf(p0, sW[jj], fmaf(p1, sW[16 + jj], fmaf(p2, sW[32 + jj], sb[jj])));
            o[r] = (_Float16)(fmaxf(h, 0.f) * d);
        }
        *reinterpret_cast<half8n*>(orow + q * 8) = o;
    }
}

// ------- layer2: 16-wide fp16 gather + fused W2/relu/W3 epilogue -------
// 4 lanes per node; after gather, quad all-gathers u[16] via shfl_xor and
// computes t3 = (relu(u@W2+b2)@W3)*dinv directly.

__global__ void k_g16mm(const int* __restrict__ rowptr, const int* __restrict__ ssrc,
                        const _Float16* __restrict__ t16, const float* __restrict__ dinv,
                        const float* __restrict__ W2, const float* __restrict__ b2,
                        const float* __restrict__ W3, float2* __restrict__ t3, int n) {
    __shared__ float sW2[512];
    __shared__ float sb2[32];
    __shared__ float sW3[64];
    for (int i = threadIdx.x; i < 512; i += 256) sW2[i] = W2[i];
    if (threadIdx.x < 32) sb2[threadIdx.x] = b2[threadIdx.x];
    if (threadIdx.x < 64) sW3[threadIdx.x] = W3[threadIdx.x];
    __syncthreads();

    constexpr int U = 8;
    int i = blockIdx.x * blockDim.x + threadIdx.x;
    int node = i >> 2;
    int fv = i & 3;          // quad lane: owns feats fv*4..fv*4+3
    if (node >= n) return;   // whole quads exit together (4-aligned)
    int f0 = fv * 4;

    float acc0, acc1, acc2, acc3;
    {
        half4n v = *reinterpret_cast<const half4n*>(t16 + (size_t)node * 16 + f0);
        acc0 = (float)v.x; acc1 = (float)v.y; acc2 = (float)v.z; acc3 = (float)v.w;
    }
    int beg = rowptr[node], end = rowptr[node + 1];
    int j = beg;
    for (; j + U <= end; j += U) {
        int s[U];
#pragma unroll
        for (int k = 0; k < U; ++k) s[k] = ssrc[j + k];
        half4n v[U];
#pragma unroll
        for (int k = 0; k < U; ++k)
            v[k] = *reinterpret_cast<const half4n*>(t16 + (size_t)s[k] * 16 + f0);
#pragma unroll
        for (int k = 0; k < U; ++k) {
            acc0 += (float)v[k].x; acc1 += (float)v[k].y;
            acc2 += (float)v[k].z; acc3 += (float)v[k].w;
        }
    }
    for (; j < end; ++j) {
        half4n v = *reinterpret_cast<const half4n*>(t16 + (size_t)ssrc[j] * 16 + f0);
        acc0 += (float)v.x; acc1 += (float)v.y; acc2 += (float)v.z; acc3 += (float)v.w;
    }
    float d = dinv[node];
    float q[4] = {acc0 * d, acc1 * d, acc2 * d, acc3 * d};  // u[f0..f0+3]

    // quad all-gather: p1 = quad(fv^1), p2 = quad(fv^2), p3 = quad(fv^3)
    float p1[4], p2[4], p3[4];
#pragma unroll
    for (int c = 0; c < 4; ++c) p1[c] = __shfl_xor(q[c], 1);
#pragma unroll
    for (int c = 0; c < 4; ++c) { p2[c] = __shfl_xor(q[c], 2); p3[c] = __shfl_xor(p1[c], 2); }

    float uu[16];
#pragma unroll
    for (int c = 0; c < 4; ++c) {
        uu[0 + c]  = fv == 0 ? q[c] : fv == 1 ? p1[c] : fv == 2 ? p2[c] : p3[c];
        uu[4 + c]  = fv == 1 ? q[c] : fv == 0 ? p1[c] : fv == 3 ? p2[c] : p3[c];
        uu[8 + c]  = fv == 2 ? q[c] : fv == 3 ? p1[c] : fv == 0 ? p2[c] : p3[c];
        uu[12 + c] = fv == 3 ? q[c] : fv == 2 ? p1[c] : fv == 1 ? p2[c] : p3[c];
    }

    // lane fv computes W2 columns fv*8..fv*8+7
    float t30 = 0.f, t31 = 0.f;
    int jbase = fv * 8;
#pragma unroll
    for (int r = 0; r < 8; ++r) {
        int jj = jbase + r;
        float h = sb2[jj];
#pragma unroll
        for (int k = 0; k < 16; ++k) h = fmaf(uu[k], sW2[k * 32 + jj], h);
        h = fmaxf(h, 0.f);
        t30 = fmaf(h, sW3[jj * 2 + 0], t30);
        t31 = fmaf(h, sW3[jj * 2 + 1], t31);
    }
    t30 += __shfl_xor(t30, 1); t30 += __shfl_xor(t30, 2);
    t31 += __shfl_xor(t31, 1); t31 += __shfl_xor(t31, 2);
    if (fv == 0) t3[node] = make_float2(t30 * d, t31 * d);
}

// ---------------- layer3: gather 2-wide + bias ----------------

__global__ void k_g2(const int* __restrict__ rowptr, const int* __restrict__ ssrc,
                     const float2* __restrict__ t3, const float* __restrict__ dinv,
                     const float* __restrict__ b3, float2* __restrict__ out, int n) {
    constexpr int U = 8;
    int node = blockIdx.x * blockDim.x + threadIdx.x;
    if (node >= n) return;
    float2 t = t3[node];
    float a0 = t.x, a1 = t.y;
    int beg = rowptr[node], end = rowptr[node + 1];
    int j = beg;
    for (; j + U <= end; j += U) {
        int s[U];
#pragma unroll
        for (int k = 0; k < U; ++k) s[k] = ssrc[j + k];
        float2 v[U];
#pragma unroll
        for (int k = 0; k < U; ++k) v[k] = t3[s[k]];
#pragma unroll
        for (int k = 0; k < U; ++k) { a0 += v[k].x; a1 += v[k].y; }
    }
    for (; j < end; ++j) {
        float2 v = t3[ssrc[j]];
        a0 += v.x; a1 += v.y;
    }
    float d = dinv[node];
    out[node] = make_float2(fmaf(d, a0, b3[0]), fmaf(d, a1, b3[1]));
}

// ---------------- launch ----------------

static inline size_t align256(size_t x) { return (x + 255) & ~(size_t)255; }

extern "C" void kernel_launch(void* const* d_in, const int* in_sizes, int n_in,
                              void* d_out, int out_size, void* d_ws, size_t ws_size,
                              hipStream_t stream) {
    const float* x  = (const float*)d_in[0];
    const int*   ei = (const int*)d_in[1];
    const float* W1 = (const float*)d_in[2];
    const float* b1 = (const float*)d_in[3];
    const float* W2 = (const float*)d_in[4];
    const float* b2 = (const float*)d_in[5];
    const float* W3 = (const float*)d_in[6];
    const float* b3 = (const float*)d_in[7];
    float2* out = (float2*)d_out;

    const int* src = ei;
    const int* dst = ei + NED;

    char* p = (char*)d_ws;
    float* dinv   = (float*)p; p += align256(sizeof(float) * (size_t)NND);
    int*   rowptr = (int*)p;   p += align256(sizeof(int) * (size_t)(NND + 1));
    int*   excl   = (int*)p;   p += align256(sizeof(int) * (size_t)(SCAN_N + 1));
    int*   bsums  = (int*)p;   p += align256(sizeof(int) * 128);
    int*   ssrc   = (int*)p;   p += align256(sizeof(int) * (size_t)NED);
    float4* t4    = (float4*)p; p += align256(sizeof(float4) * (size_t)NND);
    float2* t3    = (float2*)p; p += align256(sizeof(float2) * (size_t)NND);
    // region shared by tmp (dead after k_bucket) and t16 (written after)
    char*  q      = p;         p += align256(sizeof(int) * (size_t)NED);
    int*   tmp    = (int*)q;
    _Float16* t16 = (_Float16*)q;                                // [NND][16] fp16

    const int B = 256;
    const int gridN = (NND + B - 1) / B;
    const int grid4N = (NND * 4 + B - 1) / B;
    const int nScanBlocks = (SCAN_N + 1023) / 1024;  // 98

    // ---- CSR build (+ fused layer-1 prep in k_bucket) ----
    k_hist<<<NCHUNK, B, 0, stream>>>(dst, excl);
    k_scan1<<<nScanBlocks, 256, 0, stream>>>(excl, excl, bsums, SCAN_N);
    k_scan2<<<1, 128, 0, stream>>>(bsums, nScanBlocks);
    k_scan3<<<(SCAN_N + 1 + B - 1) / B, B, 0, stream>>>(excl, bsums, SCAN_N, NED);
    k_part<<<NCHUNK, B, 0, stream>>>(src, dst, excl, tmp);
    k_bucket<<<NB, B, 0, stream>>>(excl, tmp, ssrc, rowptr, dinv, x, t4);

    // ---- layer 1: aggregate 4-wide, fused 3->16, fp16 table out ----
    k_g4mm1<<<gridN, B, 0, stream>>>(rowptr, ssrc, t4, dinv, W1, b1, t16, NND);

    // ---- layer 2: 16-wide fp16 gather + fused W2/relu/W3 -> t3 ----
    k_g16mm<<<grid4N, B, 0, stream>>>(rowptr, ssrc, t16, dinv, W2, b2, W3, t3, NND);

    // ---- layer 3: gather 2-wide ----
    k_g2<<<gridN, B, 0, stream>>>(rowptr, ssrc, t3, dinv, b3, out, NND);
}